// Round 2
// baseline (32.709 us; speedup 1.0000x reference)
//
#include <hip/hip_runtime.h>

typedef __attribute__((ext_vector_type(4))) float float4v;

// Output: [B=32, T=577, D=768] float32.
// t==0 -> cls_token[b, :]; t>=1 -> patch q=t-1: hp=q/24, wp=q%24,
// d = c*256 + i*16 + j -> img[b, c, hp*16+i, wp*16+j]. Plus pos[t, d].
__global__ __launch_bounds__(256) void patch_embed_kernel(
    const float* __restrict__ img, const float* __restrict__ cls,
    const float* __restrict__ pos, float* __restrict__ out, int total4)
{
    int v = blockIdx.x * blockDim.x + threadIdx.x;
    if (v >= total4) return;

    const int DIM4 = 192;  // 768/4
    const int NTOK = 577;  // 1 + 24*24

    int t_idx = v / DIM4;
    int d4    = v - t_idx * DIM4;
    int b     = t_idx / NTOK;
    int t     = t_idx - b * NTOK;
    int d     = d4 * 4;

    const float* srcp;
    if (t == 0) {
        srcp = cls + (size_t)b * 768 + d;
    } else {
        int q   = t - 1;
        int hp  = q / 24;
        int wp  = q - hp * 24;
        int c   = d >> 8;        // d / 256
        int rem = d & 255;
        int i   = rem >> 4;      // (d%256)/16
        int j   = rem & 15;      // 0,4,8,12
        size_t off = (((size_t)(b * 3 + c) * 384) + hp * 16 + i) * 384
                     + wp * 16 + j;
        srcp = img + off;
    }

    float4v sv = *(const float4v*)srcp;
    float4v pv = *(const float4v*)(pos + (size_t)t * 768 + d);
    float4v ov = sv + pv;
    *(float4v*)(out + (size_t)v * 4) = ov;
}

extern "C" void kernel_launch(void* const* d_in, const int* in_sizes, int n_in,
                              void* d_out, int out_size, void* d_ws, size_t ws_size,
                              hipStream_t stream) {
    const float* img = (const float*)d_in[0];   // [32,3,384,384] f32
    const float* cls = (const float*)d_in[1];   // [32,768]       f32
    const float* pos = (const float*)d_in[2];   // [577,768]      f32
    float* out = (float*)d_out;                 // [32,577,768]   f32

    int total4 = out_size / 4;                  // 3,544,704 float4s
    int block = 256;
    int grid = (total4 + block - 1) / block;
    patch_embed_kernel<<<grid, block, 0, stream>>>(img, cls, pos, out, total4);
}

// Round 3
// 32.659 us; speedup vs baseline: 1.0015x; 1.0015x over previous
//
#include <hip/hip_runtime.h>

typedef __attribute__((ext_vector_type(4))) float float4v;

// Output: [B=32, T=577, D=768] float32.
// t==0 -> cls_token[b, :]; t>=1 -> patch q=t-1: hp=q/24, wp=q%24,
// d = c*256 + i*16 + j -> img[b, c, hp*16+i, wp*16+j]. Plus pos[t, d].
__device__ __forceinline__ const float* src_addr(
    const float* __restrict__ img, const float* __restrict__ cls,
    int v, int* t_out, int* d_out)
{
    const int DIM4 = 192;  // 768/4
    const int NTOK = 577;  // 1 + 24*24

    int t_idx = v / DIM4;
    int d4    = v - t_idx * DIM4;
    int b     = t_idx / NTOK;
    int t     = t_idx - b * NTOK;
    int d     = d4 * 4;
    *t_out = t; *d_out = d;

    if (t == 0) {
        return cls + (size_t)b * 768 + d;
    }
    int q   = t - 1;
    int hp  = q / 24;
    int wp  = q - hp * 24;
    int c   = d >> 8;        // d / 256
    int rem = d & 255;
    int i   = rem >> 4;      // (d%256)/16
    int j   = rem & 15;      // 0,4,8,12
    size_t off = (((size_t)(b * 3 + c) * 384) + hp * 16 + i) * 384
                 + wp * 16 + j;
    return img + off;
}

__global__ __launch_bounds__(256) void patch_embed_kernel(
    const float* __restrict__ img, const float* __restrict__ cls,
    const float* __restrict__ pos, float* __restrict__ out, int total4)
{
    const int stride = gridDim.x * blockDim.x;
    int v = blockIdx.x * blockDim.x + threadIdx.x;

    // Jammed 4-wide main loop: 8 independent loads in flight, then 4 stores.
    for (; v + 3 * stride < total4; v += 4 * stride) {
        int t0, t1, t2, t3, d0, d1, d2, d3;
        const float* s0p = src_addr(img, cls, v + 0 * stride, &t0, &d0);
        const float* s1p = src_addr(img, cls, v + 1 * stride, &t1, &d1);
        const float* s2p = src_addr(img, cls, v + 2 * stride, &t2, &d2);
        const float* s3p = src_addr(img, cls, v + 3 * stride, &t3, &d3);
        float4v s0 = *(const float4v*)s0p;
        float4v s1 = *(const float4v*)s1p;
        float4v s2 = *(const float4v*)s2p;
        float4v s3 = *(const float4v*)s3p;
        float4v p0 = *(const float4v*)(pos + (size_t)t0 * 768 + d0);
        float4v p1 = *(const float4v*)(pos + (size_t)t1 * 768 + d1);
        float4v p2 = *(const float4v*)(pos + (size_t)t2 * 768 + d2);
        float4v p3 = *(const float4v*)(pos + (size_t)t3 * 768 + d3);
        __builtin_nontemporal_store(s0 + p0, (float4v*)(out + (size_t)(v + 0 * stride) * 4));
        __builtin_nontemporal_store(s1 + p1, (float4v*)(out + (size_t)(v + 1 * stride) * 4));
        __builtin_nontemporal_store(s2 + p2, (float4v*)(out + (size_t)(v + 2 * stride) * 4));
        __builtin_nontemporal_store(s3 + p3, (float4v*)(out + (size_t)(v + 3 * stride) * 4));
    }
    // Tail
    for (; v < total4; v += stride) {
        int t, d;
        const float* sp = src_addr(img, cls, v, &t, &d);
        float4v s = *(const float4v*)sp;
        float4v p = *(const float4v*)(pos + (size_t)t * 768 + d);
        __builtin_nontemporal_store(s + p, (float4v*)(out + (size_t)v * 4));
    }
}

extern "C" void kernel_launch(void* const* d_in, const int* in_sizes, int n_in,
                              void* d_out, int out_size, void* d_ws, size_t ws_size,
                              hipStream_t stream) {
    const float* img = (const float*)d_in[0];   // [32,3,384,384] f32
    const float* cls = (const float*)d_in[1];   // [32,768]       f32
    const float* pos = (const float*)d_in[2];   // [577,768]      f32
    float* out = (float*)d_out;                 // [32,577,768]   f32

    int total4 = out_size / 4;                  // 3,544,704 float4s
    int block = 256;
    int grid = 1728;                            // 8×216: XCD-multiple, ~8 f4/thread
    patch_embed_kernel<<<grid, block, 0, stream>>>(img, cls, pos, out, total4);
}

// Round 4
// 22.469 us; speedup vs baseline: 1.4557x; 1.4535x over previous
//
#include <hip/hip_runtime.h>

typedef __attribute__((ext_vector_type(4))) float float4v;

#define LDS_STRIDE 392  // 384 + 8 pad: <=2-way bank aliasing both phases (free)

// out[b, t, d], B=32, T=577, D=768.
// t==0: cls[b,:] + pos[0,:].
// t>=1: q=t-1, hp=q/24, wp=q%24; d=c*256+i*16+jj -> img[b,c,hp*16+i,wp*16+jj].
// Block (b,c,hp) stages the contiguous slab img[b,c,hp*16:(hp+1)*16,:]
// (16x384 floats = 24.6KB) in LDS, then writes 24 contiguous 1KB token-chunks.
__global__ __launch_bounds__(256) void patch_embed_kernel(
    const float* __restrict__ img, const float* __restrict__ cls,
    const float* __restrict__ pos, float* __restrict__ out)
{
    __shared__ __align__(16) float lds[16 * LDS_STRIDE];
    const int tid = threadIdx.x;
    const int bid = blockIdx.x;

    if (bid < 2304) {                       // 32*3*24 slabs
        int b   = bid / 72;
        int rem = bid - b * 72;
        int c   = rem / 24;
        int hp  = rem - c * 24;

        const float* slab = img + (((size_t)(b * 3 + c) * 384) + hp * 16) * 384;

        #pragma unroll
        for (int k = 0; k < 6; ++k) {
            int fidx = k * 256 + tid;       // float4 index in slab [0,1536)
            int i    = fidx / 96;           // img row 0..15
            int wq   = fidx - i * 96;       // float4 within row
            float4v v = *(const float4v*)(slab + (size_t)fidx * 4);
            *(float4v*)(&lds[i * LDS_STRIDE + wq * 4]) = v;
        }
        __syncthreads();

        size_t out_base = ((size_t)b * 577 + (size_t)hp * 24 + 1) * 768 + c * 256;
        int    pos_base = (hp * 24 + 1) * 768 + c * 256;
        #pragma unroll
        for (int k = 0; k < 6; ++k) {
            int m  = k * 256 + tid;
            int wp = m >> 6;                // token within patch-row, 0..23
            int l  = m & 63;                // float4 within 256-float chunk
            int i  = l >> 2;
            int j4 = l & 3;
            float4v v = *(const float4v*)(&lds[i * LDS_STRIDE + wp * 16 + j4 * 4]);
            int doff = i * 16 + j4 * 4;
            float4v p = *(const float4v*)(pos + pos_base + wp * 768 + doff);
            *(float4v*)(out + out_base + (size_t)wp * 768 + doff) = v + p;
        }
    } else {
        // cls tokens: 24 blocks x 256 threads = 6144 float4s = 32x768 floats
        int idx = (bid - 2304) * 256 + tid;
        int b   = idx / 192;
        int d4  = idx - b * 192;
        float4v v = *(const float4v*)(cls + (size_t)b * 768 + (size_t)d4 * 4);
        float4v p = *(const float4v*)(pos + (size_t)d4 * 4);
        *(float4v*)(out + ((size_t)b * 577) * 768 + (size_t)d4 * 4) = v + p;
    }
}

extern "C" void kernel_launch(void* const* d_in, const int* in_sizes, int n_in,
                              void* d_out, int out_size, void* d_ws, size_t ws_size,
                              hipStream_t stream) {
    const float* img = (const float*)d_in[0];   // [32,3,384,384] f32
    const float* cls = (const float*)d_in[1];   // [32,768]       f32
    const float* pos = (const float*)d_in[2];   // [577,768]      f32
    float* out = (float*)d_out;                 // [32,577,768]   f32

    int grid = 2304 + 24;                       // patch slabs + cls blocks
    patch_embed_kernel<<<grid, 256, 0, stream>>>(img, cls, pos, out);
}

// Round 5
// 21.743 us; speedup vs baseline: 1.5043x; 1.0334x over previous
//
#include <hip/hip_runtime.h>

typedef __attribute__((ext_vector_type(4))) float float4v;

#define STRIDE 392  // 384 + 8 pad: <=2-way bank aliasing (free)

// out[b, t, d], B=32, T=577, D=768 (f32).
// t==0: cls[b,:] + pos[0,:].
// t>=1: q=t-1, hp=q/24, wp=q%24; d=c*256+i*16+jj -> img[b,c,hp*16+i,wp*16+jj].
//
// Unit u = ((b*3+c)*24+hp)*2+h stages 8 contiguous img rows (12.3KB) in LDS,
// then writes 24 tokens x 512B contiguous out runs. Grid = 1536 blocks
// (exactly 6/CU, LDS 25KB dbuf), each block = exactly 3 units -> no tail.
__global__ __launch_bounds__(256) void patch_embed_kernel(
    const float* __restrict__ img, const float* __restrict__ cls,
    const float* __restrict__ pos, float* __restrict__ out)
{
    __shared__ __align__(16) float lds[2][8 * STRIDE];
    const int tid = threadIdx.x;
    const int bid = blockIdx.x;

    // cls prefetch (blocks 0..23): 24*256 float4 = 32x768 floats; store at end.
    bool do_cls = (bid < 24);
    float4v cv, cpv;
    size_t cout = 0;
    if (do_cls) {
        int idx = bid * 256 + tid;          // 0..6143
        int b   = idx / 192;
        int d4  = idx - b * 192;
        cv  = *(const float4v*)(cls + (size_t)b * 768 + (size_t)d4 * 4);
        cpv = *(const float4v*)(pos + (size_t)d4 * 4);
        cout = ((size_t)b * 577) * 768 + (size_t)d4 * 4;
    }

    auto load_unit = [&](int u, int buf) {
        int b  = u / 144;                   // 144 = 3*24*2 units per image
        int r  = u - b * 144;
        int c  = r / 48;
        int r2 = r - c * 48;
        int hp = r2 >> 1;
        int h  = r2 & 1;
        const float* slab =
            img + (((size_t)(b * 3 + c) * 384) + hp * 16 + h * 8) * 384;
        #pragma unroll
        for (int k = 0; k < 3; ++k) {
            int fidx = k * 256 + tid;       // 0..767 float4s (8 rows x 96)
            int row  = fidx / 96;
            int wq   = fidx - row * 96;
            float4v v = *(const float4v*)(slab + (size_t)fidx * 4);
            *(float4v*)(&lds[buf][row * STRIDE + wq * 4]) = v;
        }
    };

    auto store_unit = [&](int u, int buf) {
        int b  = u / 144;
        int r  = u - b * 144;
        int c  = r / 48;
        int r2 = r - c * 48;
        int hp = r2 >> 1;
        int h  = r2 & 1;
        #pragma unroll
        for (int k = 0; k < 3; ++k) {
            int m  = k * 256 + tid;         // 0..767
            int wp = m >> 5;                // token in patch-row, 0..23
            int l  = m & 31;                // float4 within 128-float run
            int i  = l >> 2;                // local row 0..7
            int j4 = l & 3;
            float4v v = *(const float4v*)(&lds[buf][i * STRIDE + wp * 16 + j4 * 4]);
            int doff = c * 256 + (h * 8 + i) * 16 + j4 * 4;
            int trow = hp * 24 + wp + 1;
            float4v p = *(const float4v*)(pos + (size_t)trow * 768 + doff);
            *(float4v*)(out + ((size_t)b * 577 + trow) * 768 + doff) = v + p;
        }
    };

    int u0 = bid * 3;
    load_unit(u0 + 0, 0);
    __syncthreads();
    load_unit(u0 + 1, 1);
    store_unit(u0 + 0, 0);
    __syncthreads();
    load_unit(u0 + 2, 0);
    store_unit(u0 + 1, 1);
    __syncthreads();
    store_unit(u0 + 2, 0);

    if (do_cls) {
        *(float4v*)(out + cout) = cv + cpv;
    }
}

extern "C" void kernel_launch(void* const* d_in, const int* in_sizes, int n_in,
                              void* d_out, int out_size, void* d_ws, size_t ws_size,
                              hipStream_t stream) {
    const float* img = (const float*)d_in[0];   // [32,3,384,384] f32
    const float* cls = (const float*)d_in[1];   // [32,768]       f32
    const float* pos = (const float*)d_in[2];   // [577,768]      f32
    float* out = (float*)d_out;                 // [32,577,768]   f32

    patch_embed_kernel<<<1536, 256, 0, stream>>>(img, cls, pos, out);
}